// Round 2
// baseline (6273.579 us; speedup 1.0000x reference)
//
#include <hip/hip_runtime.h>

#define N_NODES   100000
#define N_EDGES   3200000
#define HIDDEN    64
#define NUM_GRAPHS 128

// ---------------- zero fill (float4) ----------------
__global__ void zero4_kernel(float4* __restrict__ p, int n4) {
    int i = blockIdx.x * blockDim.x + threadIdx.x;
    if (i < n4) p[i] = make_float4(0.f, 0.f, 0.f, 0.f);
}

// ---------------- degree via atomics ----------------
__global__ void deg_kernel(const int* __restrict__ dst, const float* __restrict__ ew,
                           float* __restrict__ deg, int E) {
    int i = blockIdx.x * blockDim.x + threadIdx.x;
    if (i < E) atomicAdd(&deg[dst[i]], ew[i]);
}

__global__ void dinv_kernel(const float* __restrict__ deg, float* __restrict__ dinv, int n) {
    int i = blockIdx.x * blockDim.x + threadIdx.x;
    if (i < n) dinv[i] = rsqrtf(deg[i] + 1.0f);
}

// ---------------- H[N,64] = X[N,64] @ W[64,64] ----------------
// If labels != nullptr, row r of X is emb[labels[r]].
__global__ __launch_bounds__(256) void gemm64_kernel(
    const float* __restrict__ X, const int* __restrict__ labels,
    const float* __restrict__ emb, const float* __restrict__ W,
    float* __restrict__ H, int n) {
    __shared__ float Ws[64 * 64];
    __shared__ float Xs[64 * 65];   // +1 pad: lane=row LDS reads conflict-free
    int t = threadIdx.x;

    // load W (64x64, row-major [k][j]) coalesced
    #pragma unroll
    for (int s = 0; s < 16; ++s) Ws[s * 256 + t] = W[s * 256 + t];

    // load X tile: 64 rows x 64 cols; thread -> (row = t>>2, 16 cols)
    int r0   = blockIdx.x * 64;
    int lrow = t >> 2;
    int c0   = (t & 3) * 16;
    int grow = r0 + lrow;
    const float* srcrow;
    if (grow < n) {
        srcrow = labels ? (emb + (size_t)labels[grow] * HIDDEN)
                        : (X   + (size_t)grow * HIDDEN);
    } else {
        srcrow = labels ? emb : X;   // dummy valid row
    }
    #pragma unroll
    for (int c = 0; c < 16; c += 4) {
        float4 v = *(const float4*)(srcrow + c0 + c);
        Xs[lrow * 65 + c0 + c + 0] = v.x;
        Xs[lrow * 65 + c0 + c + 1] = v.y;
        Xs[lrow * 65 + c0 + c + 2] = v.z;
        Xs[lrow * 65 + c0 + c + 3] = v.w;
    }
    __syncthreads();

    // compute: wave w handles j-block w*16; lane = row
    int row = t & 63;
    int j0  = (t >> 6) * 16;
    float4 a0 = make_float4(0,0,0,0), a1 = a0, a2 = a0, a3 = a0;
    #pragma unroll
    for (int k = 0; k < 64; ++k) {
        float xv = Xs[row * 65 + k];
        const float4* wr = (const float4*)(Ws + k * 64 + j0);
        float4 w0 = wr[0], w1 = wr[1], w2 = wr[2], w3 = wr[3];
        a0.x = fmaf(xv, w0.x, a0.x); a0.y = fmaf(xv, w0.y, a0.y);
        a0.z = fmaf(xv, w0.z, a0.z); a0.w = fmaf(xv, w0.w, a0.w);
        a1.x = fmaf(xv, w1.x, a1.x); a1.y = fmaf(xv, w1.y, a1.y);
        a1.z = fmaf(xv, w1.z, a1.z); a1.w = fmaf(xv, w1.w, a1.w);
        a2.x = fmaf(xv, w2.x, a2.x); a2.y = fmaf(xv, w2.y, a2.y);
        a2.z = fmaf(xv, w2.z, a2.z); a2.w = fmaf(xv, w2.w, a2.w);
        a3.x = fmaf(xv, w3.x, a3.x); a3.y = fmaf(xv, w3.y, a3.y);
        a3.w = fmaf(xv, w3.w, a3.w); a3.z = fmaf(xv, w3.z, a3.z);
    }
    int gr = r0 + row;
    if (gr < n) {
        float4* o = (float4*)(H + (size_t)gr * HIDDEN + j0);
        o[0] = a0; o[1] = a1; o[2] = a2; o[3] = a3;
    }
}

// ---------------- edge aggregation: OUT[dst] += H[src]*norm ----------------
// 16 threads per edge (float4 each); lanes 0..15 of a group share one edge.
__global__ void agg_kernel(const int* __restrict__ src, const int* __restrict__ dst,
                           const float* __restrict__ ew, const float* __restrict__ dinv,
                           const float* __restrict__ H, float* __restrict__ OUT) {
    int t = blockIdx.x * blockDim.x + threadIdx.x;
    if (t >= N_EDGES * 16) return;
    int e = t >> 4;
    int q = t & 15;
    int s = src[e], d = dst[e];
    float nrm = dinv[s] * ew[e] * dinv[d];
    float4 hv = *(const float4*)(H + (size_t)s * HIDDEN + q * 4);
    float* o = OUT + (size_t)d * HIDDEN + q * 4;
    atomicAdd(o + 0, hv.x * nrm);
    atomicAdd(o + 1, hv.y * nrm);
    atomicAdd(o + 2, hv.z * nrm);
    atomicAdd(o + 3, hv.w * nrm);
}

// ---------------- self-loop + bias + relu (in-place on A), optional pool ----------------
__global__ void post_kernel(float* __restrict__ A, const float* __restrict__ H,
                            const float* __restrict__ dinv, const float* __restrict__ b,
                            const int* __restrict__ batch, float* __restrict__ gsum,
                            float* __restrict__ gcnt, int do_pool) {
    int t = blockIdx.x * blockDim.x + threadIdx.x;
    if (t >= N_NODES * 16) return;
    int i = t >> 4;
    int q = t & 15;
    float di  = dinv[i];
    float di2 = di * di;
    size_t off = (size_t)i * HIDDEN + q * 4;
    float4 a  = *(float4*)(A + off);
    float4 h  = *(const float4*)(H + off);
    float4 bv = *(const float4*)(b + q * 4);
    float4 v;
    v.x = fmaxf(fmaf(h.x, di2, a.x) + bv.x, 0.f);
    v.y = fmaxf(fmaf(h.y, di2, a.y) + bv.y, 0.f);
    v.z = fmaxf(fmaf(h.z, di2, a.z) + bv.z, 0.f);
    v.w = fmaxf(fmaf(h.w, di2, a.w) + bv.w, 0.f);
    *(float4*)(A + off) = v;
    if (do_pool) {
        int g = batch[i];
        float* gs = gsum + (size_t)g * HIDDEN + q * 4;
        atomicAdd(gs + 0, v.x);
        atomicAdd(gs + 1, v.y);
        atomicAdd(gs + 2, v.z);
        atomicAdd(gs + 3, v.w);
        if (q == 0) atomicAdd(&gcnt[g], 1.0f);
    }
}

// ---------------- head: mean -> relu(g@W3+b3) -> @W4+b4 ----------------
__global__ void head_kernel(const float* __restrict__ gsum, const float* __restrict__ gcnt,
                            const float* __restrict__ W3, const float* __restrict__ b3,
                            const float* __restrict__ W4, const float* __restrict__ b4,
                            float* __restrict__ out) {
    __shared__ float g[64];
    int blk = blockIdx.x;
    int j = threadIdx.x;
    float cnt = fmaxf(gcnt[blk], 1.0f);
    g[j] = gsum[blk * 64 + j] / cnt;
    __syncthreads();
    float acc = b3[j];
    #pragma unroll
    for (int k = 0; k < 64; ++k) acc = fmaf(g[k], W3[k * 64 + j], acc);
    float p = fmaxf(acc, 0.f) * W4[j];
    #pragma unroll
    for (int off = 32; off > 0; off >>= 1) p += __shfl_down(p, off, 64);
    if (j == 0) out[blk] = p + b4[0];
}

extern "C" void kernel_launch(void* const* d_in, const int* in_sizes, int n_in,
                              void* d_out, int out_size, void* d_ws, size_t ws_size,
                              hipStream_t stream) {
    const int*   labels = (const int*)d_in[0];
    const int*   ei     = (const int*)d_in[1];
    const int*   src    = ei;
    const int*   dst    = ei + N_EDGES;
    const float* ew     = (const float*)d_in[2];
    const int*   batch  = (const int*)d_in[3];
    const float* emb    = (const float*)d_in[4];
    const float* W1 = (const float*)d_in[5],  *b1 = (const float*)d_in[6];
    const float* W2 = (const float*)d_in[7],  *b2 = (const float*)d_in[8];
    const float* W3 = (const float*)d_in[9],  *b3 = (const float*)d_in[10];
    const float* W4 = (const float*)d_in[11], *b4 = (const float*)d_in[12];
    float* out = (float*)d_out;

    float* ws   = (float*)d_ws;
    float* bufH = ws;                          // N*64
    float* bufA = bufH + (size_t)N_NODES * 64; // N*64 (agg target, then X)
    float* deg  = bufA + (size_t)N_NODES * 64; // N
    float* dinv = deg  + N_NODES;              // N
    float* gsum = dinv + N_NODES;              // 128*64
    float* gcnt = gsum + NUM_GRAPHS * 64;      // 128

    const int NT = 256;
    const int n64  = N_NODES * 64;                 // 6.4M
    const int blkN64_4 = (n64 / 4 + NT - 1) / NT;  // float4 zero of a big buffer
    const int blkE   = (N_EDGES + NT - 1) / NT;
    const int blkN   = (N_NODES + NT - 1) / NT;
    const int blkE16 = (N_EDGES * 16 + NT - 1) / NT;   // 200000
    const int blkN16 = (N_NODES * 16 + NT - 1) / NT;
    const int blkG   = (N_NODES + 63) / 64;            // gemm row-tiles

    // zero deg + dinv + gsum + gcnt (contiguous tail region)
    int ztail = 2 * N_NODES + NUM_GRAPHS * 64 + NUM_GRAPHS;   // 208320, %4==0
    zero4_kernel<<<(ztail / 4 + NT - 1) / NT, NT, 0, stream>>>((float4*)deg, ztail / 4);

    deg_kernel<<<blkE, NT, 0, stream>>>(dst, ew, deg, N_EDGES);
    dinv_kernel<<<blkN, NT, 0, stream>>>(deg, dinv, N_NODES);

    // ---- conv1: H = emb[labels] @ W1 ----
    gemm64_kernel<<<blkG, NT, 0, stream>>>(nullptr, labels, emb, W1, bufH, N_NODES);
    zero4_kernel<<<blkN64_4, NT, 0, stream>>>((float4*)bufA, n64 / 4);
    agg_kernel<<<blkE16, NT, 0, stream>>>(src, dst, ew, dinv, bufH, bufA);
    post_kernel<<<blkN16, NT, 0, stream>>>(bufA, bufH, dinv, b1,
                                           nullptr, nullptr, nullptr, 0);

    // ---- conv2: H = X @ W2 ----
    gemm64_kernel<<<blkG, NT, 0, stream>>>(bufA, nullptr, nullptr, W2, bufH, N_NODES);
    zero4_kernel<<<blkN64_4, NT, 0, stream>>>((float4*)bufA, n64 / 4);
    agg_kernel<<<blkE16, NT, 0, stream>>>(src, dst, ew, dinv, bufH, bufA);
    post_kernel<<<blkN16, NT, 0, stream>>>(bufA, bufH, dinv, b2,
                                           batch, gsum, gcnt, 1);

    // ---- head ----
    head_kernel<<<NUM_GRAPHS, 64, 0, stream>>>(gsum, gcnt, W3, b3, W4, b4, out);
}

// Round 3
// 813.147 us; speedup vs baseline: 7.7152x; 7.7152x over previous
//
#include <hip/hip_runtime.h>

#define N_NODES    100000
#define N_EDGES    3200000
#define HIDDEN     64
#define NUM_GRAPHS 128
#define NB_SCAN    ((N_NODES + 255) / 256)   // 391 blocks of 256

// ---------------- zero int fill ----------------
__global__ void zero_int_kernel(int* __restrict__ p, int n) {
    int i = blockIdx.x * blockDim.x + threadIdx.x;
    if (i < n) p[i] = 0;
}

// ---------------- CSR build: count ----------------
__global__ void count_kernel(const int* __restrict__ dst, int* __restrict__ cnt, int E) {
    int i = blockIdx.x * blockDim.x + threadIdx.x;
    if (i < E) atomicAdd(&cnt[dst[i]], 1);
}

// ---------------- CSR build: 2-level exclusive scan ----------------
__global__ __launch_bounds__(256) void scan_block_kernel(int* __restrict__ data,
                                                         int* __restrict__ P, int n) {
    __shared__ int a[256], b[256];
    int t = threadIdx.x;
    int i = blockIdx.x * 256 + t;
    int v = (i < n) ? data[i] : 0;
    a[t] = v; __syncthreads();
    int* pa = a; int* pb = b;
    #pragma unroll
    for (int d = 1; d < 256; d <<= 1) {
        int x = pa[t];
        if (t >= d) x += pa[t - d];
        pb[t] = x; __syncthreads();
        int* tmp = pa; pa = pb; pb = tmp;
    }
    int ex = (t == 0) ? 0 : pa[t - 1];
    if (i < n) data[i] = ex;                 // in-place block-exclusive scan
    if (t == 255) P[blockIdx.x] = pa[255];   // block total
}

__global__ __launch_bounds__(512) void scan_partials_kernel(int* __restrict__ P, int nP) {
    __shared__ int a[512], b[512];
    int t = threadIdx.x;
    int v = (t < nP) ? P[t] : 0;
    a[t] = v; __syncthreads();
    int* pa = a; int* pb = b;
    #pragma unroll
    for (int d = 1; d < 512; d <<= 1) {
        int x = pa[t];
        if (t >= d) x += pa[t - d];
        pb[t] = x; __syncthreads();
        int* tmp = pa; pa = pb; pb = tmp;
    }
    int ex = (t == 0) ? 0 : pa[t - 1];
    if (t < nP) P[t] = ex;
}

__global__ void scan_add_kernel(const int* __restrict__ cnt_scanned, const int* __restrict__ P,
                                int* __restrict__ off, int* __restrict__ cur, int n, int total) {
    int i = blockIdx.x * blockDim.x + threadIdx.x;
    if (i < n) {
        int v = cnt_scanned[i] + P[i >> 8];
        off[i] = v;
        cur[i] = v;
    }
    if (i == 0) off[n] = total;
}

// ---------------- CSR build: fill (src, ew) per edge, bucketed by dst ----------------
__global__ void fill_kernel(const int* __restrict__ src, const int* __restrict__ dst,
                            const float* __restrict__ ew, int* __restrict__ cur,
                            int2* __restrict__ csr, int E) {
    int e = blockIdx.x * blockDim.x + threadIdx.x;
    if (e < E) {
        int d = dst[e];
        int pos = atomicAdd(&cur[d], 1);
        csr[pos] = make_int2(src[e], __float_as_int(ew[e]));
    }
}

// ---------------- dinv from CSR rows (no atomics) ----------------
__global__ __launch_bounds__(256) void dinv_csr_kernel(const int2* __restrict__ csr,
                                                       const int* __restrict__ off,
                                                       float* __restrict__ dinv, int n) {
    int wid  = (blockIdx.x * blockDim.x + threadIdx.x) >> 6;
    int lane = threadIdx.x & 63;
    if (wid >= n) return;
    int s = off[wid], e = off[wid + 1];
    float sum = 0.f;
    for (int i = s + lane; i < e; i += 64) sum += __int_as_float(csr[i].y);
    #pragma unroll
    for (int o = 32; o > 0; o >>= 1) sum += __shfl_down(sum, o, 64);
    if (lane == 0) dinv[wid] = rsqrtf(sum + 1.0f);
}

// ---------------- H[N,64] = X[N,64] @ W[64,64] (labels -> emb gather) ----------------
__global__ __launch_bounds__(256) void gemm64_kernel(
    const float* __restrict__ X, const int* __restrict__ labels,
    const float* __restrict__ emb, const float* __restrict__ W,
    float* __restrict__ H, int n) {
    __shared__ float Ws[64 * 64];
    __shared__ float Xs[64 * 65];
    int t = threadIdx.x;
    #pragma unroll
    for (int s = 0; s < 16; ++s) Ws[s * 256 + t] = W[s * 256 + t];
    int r0   = blockIdx.x * 64;
    int lrow = t >> 2;
    int c0   = (t & 3) * 16;
    int grow = r0 + lrow;
    const float* srcrow;
    if (grow < n) {
        srcrow = labels ? (emb + (size_t)labels[grow] * HIDDEN)
                        : (X   + (size_t)grow * HIDDEN);
    } else {
        srcrow = labels ? emb : X;
    }
    #pragma unroll
    for (int c = 0; c < 16; c += 4) {
        float4 v = *(const float4*)(srcrow + c0 + c);
        Xs[lrow * 65 + c0 + c + 0] = v.x;
        Xs[lrow * 65 + c0 + c + 1] = v.y;
        Xs[lrow * 65 + c0 + c + 2] = v.z;
        Xs[lrow * 65 + c0 + c + 3] = v.w;
    }
    __syncthreads();
    int row = t & 63;
    int j0  = (t >> 6) * 16;
    float4 a0 = make_float4(0,0,0,0), a1 = a0, a2 = a0, a3 = a0;
    #pragma unroll
    for (int k = 0; k < 64; ++k) {
        float xv = Xs[row * 65 + k];
        const float4* wr = (const float4*)(Ws + k * 64 + j0);
        float4 w0 = wr[0], w1 = wr[1], w2 = wr[2], w3 = wr[3];
        a0.x = fmaf(xv, w0.x, a0.x); a0.y = fmaf(xv, w0.y, a0.y);
        a0.z = fmaf(xv, w0.z, a0.z); a0.w = fmaf(xv, w0.w, a0.w);
        a1.x = fmaf(xv, w1.x, a1.x); a1.y = fmaf(xv, w1.y, a1.y);
        a1.z = fmaf(xv, w1.z, a1.z); a1.w = fmaf(xv, w1.w, a1.w);
        a2.x = fmaf(xv, w2.x, a2.x); a2.y = fmaf(xv, w2.y, a2.y);
        a2.z = fmaf(xv, w2.z, a2.z); a2.w = fmaf(xv, w2.w, a2.w);
        a3.x = fmaf(xv, w3.x, a3.x); a3.y = fmaf(xv, w3.y, a3.y);
        a3.z = fmaf(xv, w3.z, a3.z); a3.w = fmaf(xv, w3.w, a3.w);
    }
    int gr = r0 + row;
    if (gr < n) {
        float4* o = (float4*)(H + (size_t)gr * HIDDEN + j0);
        o[0] = a0; o[1] = a1; o[2] = a2; o[3] = a3;
    }
}

// ---------------- pull aggregation + self-loop + bias + relu, one store per node ----------------
// one wave per dst node; lane = (g,q): g=edge subgroup (4), q=col group (16 x float4)
__global__ __launch_bounds__(256) void agg_csr_kernel(
    const float* __restrict__ H, const int2* __restrict__ csr,
    const int* __restrict__ off, const float* __restrict__ dinv,
    const float* __restrict__ bias, float* __restrict__ OUT, int n) {
    int wid  = (blockIdx.x * blockDim.x + threadIdx.x) >> 6;
    if (wid >= n) return;
    int lane = threadIdx.x & 63;
    int q = lane & 15, g = lane >> 4;
    int start = off[wid], end = off[wid + 1];
    float4 acc = make_float4(0.f, 0.f, 0.f, 0.f);
    int i = start + g;
    int2 ent = (i < end) ? csr[i] : make_int2(0, 0);
    while (i < end) {
        int inext = i + 4;
        int2 entn = (inext < end) ? csr[inext] : make_int2(0, 0);
        int s = ent.x;
        float w = __int_as_float(ent.y) * dinv[s];
        float4 h = *(const float4*)(H + (size_t)s * HIDDEN + q * 4);
        acc.x = fmaf(h.x, w, acc.x);
        acc.y = fmaf(h.y, w, acc.y);
        acc.z = fmaf(h.z, w, acc.z);
        acc.w = fmaf(h.w, w, acc.w);
        ent = entn; i = inext;
    }
    // reduce the 4 edge-subgroups (lane bits 4,5)
    acc.x += __shfl_xor(acc.x, 16, 64); acc.y += __shfl_xor(acc.y, 16, 64);
    acc.z += __shfl_xor(acc.z, 16, 64); acc.w += __shfl_xor(acc.w, 16, 64);
    acc.x += __shfl_xor(acc.x, 32, 64); acc.y += __shfl_xor(acc.y, 32, 64);
    acc.z += __shfl_xor(acc.z, 32, 64); acc.w += __shfl_xor(acc.w, 32, 64);
    if (g == 0) {
        float di  = dinv[wid];
        float di2 = di * di;
        float4 hd = *(const float4*)(H + (size_t)wid * HIDDEN + q * 4);
        float4 bv = *(const float4*)(bias + q * 4);
        float4 v;
        v.x = fmaxf(fmaf(acc.x, di, fmaf(hd.x, di2, bv.x)), 0.f);
        v.y = fmaxf(fmaf(acc.y, di, fmaf(hd.y, di2, bv.y)), 0.f);
        v.z = fmaxf(fmaf(acc.z, di, fmaf(hd.z, di2, bv.z)), 0.f);
        v.w = fmaxf(fmaf(acc.w, di, fmaf(hd.w, di2, bv.w)), 0.f);
        *(float4*)(OUT + (size_t)wid * HIDDEN + q * 4) = v;
    }
}

// ---------------- fused mean-pool (binary search on sorted batch) + MLP head ----------------
__global__ __launch_bounds__(256) void pool_head_kernel(
    const float* __restrict__ A, const int* __restrict__ batch,
    const float* __restrict__ W3, const float* __restrict__ b3,
    const float* __restrict__ W4, const float* __restrict__ b4,
    float* __restrict__ out) {
    __shared__ int   sb[2];
    __shared__ float sd[4][64];
    __shared__ float gv[64];
    int gidx = blockIdx.x;
    int t = threadIdx.x;
    if (t < 2) {
        int target = gidx + t;
        int lo = 0, hi = N_NODES;
        while (lo < hi) {
            int mid = (lo + hi) >> 1;
            if (batch[mid] < target) lo = mid + 1; else hi = mid;
        }
        sb[t] = lo;
    }
    __syncthreads();
    int start = sb[0], end = sb[1];
    int col = t & 63, rg = t >> 6;
    float sum = 0.f;
    for (int r = start + rg; r < end; r += 4) sum += A[(size_t)r * HIDDEN + col];
    sd[rg][col] = sum;
    __syncthreads();
    if (t < 64) {
        float tot = sd[0][col] + sd[1][col] + sd[2][col] + sd[3][col];
        float cnt = (float)(end - start);
        gv[col] = tot / fmaxf(cnt, 1.0f);
    }
    __syncthreads();
    if (t < 64) {
        float acc = b3[t];
        #pragma unroll
        for (int k = 0; k < 64; ++k) acc = fmaf(gv[k], W3[k * 64 + t], acc);
        float p = fmaxf(acc, 0.f) * W4[t];
        #pragma unroll
        for (int o = 32; o > 0; o >>= 1) p += __shfl_down(p, o, 64);
        if (t == 0) out[gidx] = p + b4[0];
    }
}

extern "C" void kernel_launch(void* const* d_in, const int* in_sizes, int n_in,
                              void* d_out, int out_size, void* d_ws, size_t ws_size,
                              hipStream_t stream) {
    const int*   labels = (const int*)d_in[0];
    const int*   ei     = (const int*)d_in[1];
    const int*   src    = ei;
    const int*   dst    = ei + N_EDGES;
    const float* ew     = (const float*)d_in[2];
    const int*   batch  = (const int*)d_in[3];
    const float* emb    = (const float*)d_in[4];
    const float* W1 = (const float*)d_in[5],  *b1 = (const float*)d_in[6];
    const float* W2 = (const float*)d_in[7],  *b2 = (const float*)d_in[8];
    const float* W3 = (const float*)d_in[9],  *b3 = (const float*)d_in[10];
    const float* W4 = (const float*)d_in[11], *b4 = (const float*)d_in[12];
    float* out = (float*)d_out;

    // workspace carve (4-byte words); csr at 8B-aligned offset
    float* ws   = (float*)d_ws;
    float* bufH = ws;                                   // N*64 floats
    float* bufA = bufH + (size_t)N_NODES * HIDDEN;      // N*64 floats
    int2*  csr  = (int2*)(bufA + (size_t)N_NODES * HIDDEN); // E int2 (8B each)
    int*   cnt  = (int*)(csr + N_EDGES);                // N
    int*   off  = cnt + N_NODES;                        // N+1
    int*   cur  = off + N_NODES + 1;                    // N
    int*   P    = cur + N_NODES;                        // 512
    float* dinv = (float*)(P + 512);                    // N

    const int NT = 256;
    const int blkE  = (N_EDGES + NT - 1) / NT;          // 12500
    const int blkN  = (N_NODES + NT - 1) / NT;          // 391
    const int blkW  = (N_NODES * 64 + NT - 1) / NT;     // 25000 (wave per node)
    const int blkG  = (N_NODES + 63) / 64;              // 1563

    // ---- CSR build (reused by both convs) ----
    zero_int_kernel<<<blkN, NT, 0, stream>>>(cnt, N_NODES);
    count_kernel<<<blkE, NT, 0, stream>>>(dst, cnt, N_EDGES);
    scan_block_kernel<<<NB_SCAN, NT, 0, stream>>>(cnt, P, N_NODES);
    scan_partials_kernel<<<1, 512, 0, stream>>>(P, NB_SCAN);
    scan_add_kernel<<<blkN, NT, 0, stream>>>(cnt, P, off, cur, N_NODES, N_EDGES);
    fill_kernel<<<blkE, NT, 0, stream>>>(src, dst, ew, cur, csr, N_EDGES);
    dinv_csr_kernel<<<blkW, NT, 0, stream>>>(csr, off, dinv, N_NODES);

    // ---- conv1: H = emb[labels] @ W1 ; A = relu(agg + selfloop + b1) ----
    gemm64_kernel<<<blkG, NT, 0, stream>>>(nullptr, labels, emb, W1, bufH, N_NODES);
    agg_csr_kernel<<<blkW, NT, 0, stream>>>(bufH, csr, off, dinv, b1, bufA, N_NODES);

    // ---- conv2 ----
    gemm64_kernel<<<blkG, NT, 0, stream>>>(bufA, nullptr, nullptr, W2, bufH, N_NODES);
    agg_csr_kernel<<<blkW, NT, 0, stream>>>(bufH, csr, off, dinv, b2, bufA, N_NODES);

    // ---- fused mean-pool + head ----
    pool_head_kernel<<<NUM_GRAPHS, NT, 0, stream>>>(bufA, batch, W3, b3, W4, b4, out);
}

// Round 4
// 552.750 us; speedup vs baseline: 11.3498x; 1.4711x over previous
//
#include <hip/hip_runtime.h>

#define N_NODES    100000
#define N_EDGES    3200000
#define HIDDEN     64
#define NUM_GRAPHS 128

#define BKT_SHIFT  7
#define NPB        128                              // nodes per bucket
#define NBKT       ((N_NODES + NPB - 1) / NPB)      // 782
#define CHUNK      8192
#define NBLK_E     ((N_EDGES + CHUNK - 1) / CHUNK)  // 391
#define ENTCAP     5632                             // LDS staging capacity (45 KB)

// ---------------- zero int fill ----------------
__global__ void zero_int_kernel(int* __restrict__ p, int n) {
    int i = blockIdx.x * blockDim.x + threadIdx.x;
    if (i < n) p[i] = 0;
}

// ---------------- K1: bucket histogram ----------------
__global__ __launch_bounds__(256) void hist_kernel(const int* __restrict__ dst,
                                                   int* __restrict__ bcnt, int E) {
    __shared__ int h[NBKT];
    int t = threadIdx.x;
    for (int b = t; b < NBKT; b += 256) h[b] = 0;
    __syncthreads();
    int base = blockIdx.x * CHUNK;
    int end  = min(base + CHUNK, E);
    for (int i = base + t; i < end; i += 256)
        atomicAdd(&h[dst[i] >> BKT_SHIFT], 1);
    __syncthreads();
    for (int b = t; b < NBKT; b += 256) {
        int c = h[b];
        if (c) atomicAdd(&bcnt[b], c);
    }
}

// ---------------- K2: scan bucket counts -> bucket offsets + cursors ----------------
__global__ __launch_bounds__(1024) void scan_buckets_kernel(const int* __restrict__ bcnt,
                                                            int* __restrict__ boff,
                                                            int* __restrict__ bktCur) {
    __shared__ int a[1024], b[1024];
    int t = threadIdx.x;
    int v = (t < NBKT) ? bcnt[t] : 0;
    a[t] = v; __syncthreads();
    int* pa = a; int* pb = b;
    #pragma unroll
    for (int d = 1; d < 1024; d <<= 1) {
        int x = pa[t];
        if (t >= d) x += pa[t - d];
        pb[t] = x; __syncthreads();
        int* tmp = pa; pa = pb; pb = tmp;
    }
    int ex = (t == 0) ? 0 : pa[t - 1];
    if (t < NBKT) { boff[t] = ex; bktCur[t] = ex; }
    if (t == NBKT - 1) boff[NBKT] = pa[t];
}

// ---------------- K3: scatter edges into bucket-contiguous buffer ----------------
// entry: x = src | (dstoff << 20), y = bits(ew)
__global__ __launch_bounds__(256) void bucket_scatter_kernel(
    const int* __restrict__ src, const int* __restrict__ dst,
    const float* __restrict__ ew, int* __restrict__ bktCur,
    int2* __restrict__ barr, int E) {
    __shared__ int h[NBKT];
    __shared__ int wbase[NBKT];
    int t = threadIdx.x;
    for (int b = t; b < NBKT; b += 256) h[b] = 0;
    __syncthreads();
    int base = blockIdx.x * CHUNK;
    int end  = min(base + CHUNK, E);
    for (int i = base + t; i < end; i += 256)
        atomicAdd(&h[dst[i] >> BKT_SHIFT], 1);
    __syncthreads();
    for (int b = t; b < NBKT; b += 256) {
        int c = h[b];
        wbase[b] = c ? atomicAdd(&bktCur[b], c) : 0;
    }
    __syncthreads();
    for (int b = t; b < NBKT; b += 256) h[b] = 0;
    __syncthreads();
    for (int i = base + t; i < end; i += 256) {
        int d = dst[i];
        int bk = d >> BKT_SHIFT;
        int p = atomicAdd(&h[bk], 1);
        barr[wbase[bk] + p] = make_int2(src[i] | ((d & (NPB - 1)) << 20),
                                        __float_as_int(ew[i]));
    }
}

// ---------------- K4: per-bucket finalize -> CSR + off + dinv ----------------
__global__ __launch_bounds__(256) void finalize_kernel(
    const int2* __restrict__ barr, const int* __restrict__ boff,
    int2* __restrict__ csr, int* __restrict__ off, float* __restrict__ dinv) {
    __shared__ int2  ent[ENTCAP];
    __shared__ int   hcnt[NPB];
    __shared__ float wsum[NPB];
    __shared__ int   ha[NPB], hcur[NPB];
    int b = blockIdx.x;
    int t = threadIdx.x;
    int s = boff[b], e = boff[b + 1];
    int m = e - s;
    int node0 = b << BKT_SHIFT;
    int nn = min(NPB, N_NODES - node0);
    if (t < NPB) { hcnt[t] = 0; wsum[t] = 0.f; }
    __syncthreads();
    bool staged = (m <= ENTCAP);
    // pass 1: histogram + weight sums (stage in LDS if it fits)
    for (int i = t; i < m; i += 256) {
        int2 v = barr[s + i];
        if (staged) ent[i] = v;
        int doff = (v.x >> 20) & (NPB - 1);
        atomicAdd(&hcnt[doff], 1);
        atomicAdd(&wsum[doff], __int_as_float(v.y));
    }
    __syncthreads();
    // exclusive scan over NPB counts (Hillis-Steele)
    if (t < NPB) ha[t] = hcnt[t];
    __syncthreads();
    #pragma unroll
    for (int d = 1; d < NPB; d <<= 1) {
        int x = 0;
        if (t < NPB) { x = ha[t]; if (t >= d) x += ha[t - d]; }
        __syncthreads();
        if (t < NPB) ha[t] = x;
        __syncthreads();
    }
    if (t < NPB) {
        int ex = (t == 0) ? 0 : ha[t - 1];
        hcur[t] = s + ex;
        if (t < nn) {
            off[node0 + t]  = s + ex;
            dinv[node0 + t] = rsqrtf(wsum[t] + 1.0f);
        }
    }
    if (b == NBKT - 1 && t == 0) off[N_NODES] = e;
    __syncthreads();
    // pass 2: place into final CSR window
    for (int i = t; i < m; i += 256) {
        int2 v = staged ? ent[i] : barr[s + i];
        int doff = (v.x >> 20) & (NPB - 1);
        int p = atomicAdd(&hcur[doff], 1);
        csr[p] = make_int2(v.x & 0xFFFFF, v.y);
    }
}

// ---------------- H[N,64] = X[N,64] @ W[64,64] (labels -> emb gather) ----------------
__global__ __launch_bounds__(256) void gemm64_kernel(
    const float* __restrict__ X, const int* __restrict__ labels,
    const float* __restrict__ emb, const float* __restrict__ W,
    float* __restrict__ H, int n) {
    __shared__ float Ws[64 * 64];
    __shared__ float Xs[64 * 65];
    int t = threadIdx.x;
    #pragma unroll
    for (int s = 0; s < 16; ++s) Ws[s * 256 + t] = W[s * 256 + t];
    int r0   = blockIdx.x * 64;
    int lrow = t >> 2;
    int c0   = (t & 3) * 16;
    int grow = r0 + lrow;
    const float* srcrow;
    if (grow < n) {
        srcrow = labels ? (emb + (size_t)labels[grow] * HIDDEN)
                        : (X   + (size_t)grow * HIDDEN);
    } else {
        srcrow = labels ? emb : X;
    }
    #pragma unroll
    for (int c = 0; c < 16; c += 4) {
        float4 v = *(const float4*)(srcrow + c0 + c);
        Xs[lrow * 65 + c0 + c + 0] = v.x;
        Xs[lrow * 65 + c0 + c + 1] = v.y;
        Xs[lrow * 65 + c0 + c + 2] = v.z;
        Xs[lrow * 65 + c0 + c + 3] = v.w;
    }
    __syncthreads();
    int row = t & 63;
    int j0  = (t >> 6) * 16;
    float4 a0 = make_float4(0,0,0,0), a1 = a0, a2 = a0, a3 = a0;
    #pragma unroll
    for (int k = 0; k < 64; ++k) {
        float xv = Xs[row * 65 + k];
        const float4* wr = (const float4*)(Ws + k * 64 + j0);
        float4 w0 = wr[0], w1 = wr[1], w2 = wr[2], w3 = wr[3];
        a0.x = fmaf(xv, w0.x, a0.x); a0.y = fmaf(xv, w0.y, a0.y);
        a0.z = fmaf(xv, w0.z, a0.z); a0.w = fmaf(xv, w0.w, a0.w);
        a1.x = fmaf(xv, w1.x, a1.x); a1.y = fmaf(xv, w1.y, a1.y);
        a1.z = fmaf(xv, w1.z, a1.z); a1.w = fmaf(xv, w1.w, a1.w);
        a2.x = fmaf(xv, w2.x, a2.x); a2.y = fmaf(xv, w2.y, a2.y);
        a2.z = fmaf(xv, w2.z, a2.z); a2.w = fmaf(xv, w2.w, a2.w);
        a3.x = fmaf(xv, w3.x, a3.x); a3.y = fmaf(xv, w3.y, a3.y);
        a3.z = fmaf(xv, w3.z, a3.z); a3.w = fmaf(xv, w3.w, a3.w);
    }
    int gr = r0 + row;
    if (gr < n) {
        float4* o = (float4*)(H + (size_t)gr * HIDDEN + j0);
        o[0] = a0; o[1] = a1; o[2] = a2; o[3] = a3;
    }
}

// ---------------- pull aggregation + self-loop + bias + relu ----------------
__global__ __launch_bounds__(256) void agg_csr_kernel(
    const float* __restrict__ H, const int2* __restrict__ csr,
    const int* __restrict__ off, const float* __restrict__ dinv,
    const float* __restrict__ bias, float* __restrict__ OUT, int n) {
    int wid  = (blockIdx.x * blockDim.x + threadIdx.x) >> 6;
    if (wid >= n) return;
    int lane = threadIdx.x & 63;
    int q = lane & 15, g = lane >> 4;
    int start = off[wid], end = off[wid + 1];
    float4 acc = make_float4(0.f, 0.f, 0.f, 0.f);
    int i = start + g;
    int2 ent = (i < end) ? csr[i] : make_int2(0, 0);
    while (i < end) {
        int inext = i + 4;
        int2 entn = (inext < end) ? csr[inext] : make_int2(0, 0);
        int s = ent.x;
        float w = __int_as_float(ent.y) * dinv[s];
        float4 h = *(const float4*)(H + (size_t)s * HIDDEN + q * 4);
        acc.x = fmaf(h.x, w, acc.x);
        acc.y = fmaf(h.y, w, acc.y);
        acc.z = fmaf(h.z, w, acc.z);
        acc.w = fmaf(h.w, w, acc.w);
        ent = entn; i = inext;
    }
    acc.x += __shfl_xor(acc.x, 16, 64); acc.y += __shfl_xor(acc.y, 16, 64);
    acc.z += __shfl_xor(acc.z, 16, 64); acc.w += __shfl_xor(acc.w, 16, 64);
    acc.x += __shfl_xor(acc.x, 32, 64); acc.y += __shfl_xor(acc.y, 32, 64);
    acc.z += __shfl_xor(acc.z, 32, 64); acc.w += __shfl_xor(acc.w, 32, 64);
    if (g == 0) {
        float di  = dinv[wid];
        float di2 = di * di;
        float4 hd = *(const float4*)(H + (size_t)wid * HIDDEN + q * 4);
        float4 bv = *(const float4*)(bias + q * 4);
        float4 v;
        v.x = fmaxf(fmaf(acc.x, di, fmaf(hd.x, di2, bv.x)), 0.f);
        v.y = fmaxf(fmaf(acc.y, di, fmaf(hd.y, di2, bv.y)), 0.f);
        v.z = fmaxf(fmaf(acc.z, di, fmaf(hd.z, di2, bv.z)), 0.f);
        v.w = fmaxf(fmaf(acc.w, di, fmaf(hd.w, di2, bv.w)), 0.f);
        *(float4*)(OUT + (size_t)wid * HIDDEN + q * 4) = v;
    }
}

// ---------------- fused mean-pool + MLP head ----------------
__global__ __launch_bounds__(256) void pool_head_kernel(
    const float* __restrict__ A, const int* __restrict__ batch,
    const float* __restrict__ W3, const float* __restrict__ b3,
    const float* __restrict__ W4, const float* __restrict__ b4,
    float* __restrict__ out) {
    __shared__ int   sb[2];
    __shared__ float sd[4][64];
    __shared__ float gv[64];
    int gidx = blockIdx.x;
    int t = threadIdx.x;
    if (t < 2) {
        int target = gidx + t;
        int lo = 0, hi = N_NODES;
        while (lo < hi) {
            int mid = (lo + hi) >> 1;
            if (batch[mid] < target) lo = mid + 1; else hi = mid;
        }
        sb[t] = lo;
    }
    __syncthreads();
    int start = sb[0], end = sb[1];
    int col = t & 63, rg = t >> 6;
    float sum = 0.f;
    for (int r = start + rg; r < end; r += 4) sum += A[(size_t)r * HIDDEN + col];
    sd[rg][col] = sum;
    __syncthreads();
    if (t < 64) {
        float tot = sd[0][col] + sd[1][col] + sd[2][col] + sd[3][col];
        float cnt = (float)(end - start);
        gv[col] = tot / fmaxf(cnt, 1.0f);
    }
    __syncthreads();
    if (t < 64) {
        float acc = b3[t];
        #pragma unroll
        for (int k = 0; k < 64; ++k) acc = fmaf(gv[k], W3[k * 64 + t], acc);
        float p = fmaxf(acc, 0.f) * W4[t];
        #pragma unroll
        for (int o = 32; o > 0; o >>= 1) p += __shfl_down(p, o, 64);
        if (t == 0) out[gidx] = p + b4[0];
    }
}

extern "C" void kernel_launch(void* const* d_in, const int* in_sizes, int n_in,
                              void* d_out, int out_size, void* d_ws, size_t ws_size,
                              hipStream_t stream) {
    const int*   labels = (const int*)d_in[0];
    const int*   ei     = (const int*)d_in[1];
    const int*   src    = ei;
    const int*   dst    = ei + N_EDGES;
    const float* ew     = (const float*)d_in[2];
    const int*   batch  = (const int*)d_in[3];
    const float* emb    = (const float*)d_in[4];
    const float* W1 = (const float*)d_in[5],  *b1 = (const float*)d_in[6];
    const float* W2 = (const float*)d_in[7],  *b2 = (const float*)d_in[8];
    const float* W3 = (const float*)d_in[9],  *b3 = (const float*)d_in[10];
    const float* W4 = (const float*)d_in[11], *b4 = (const float*)d_in[12];
    float* out = (float*)d_out;

    // workspace carve
    float* ws   = (float*)d_ws;
    float* bufH = ws;                                       // N*64 floats
    float* bufA = bufH + (size_t)N_NODES * HIDDEN;          // N*64 floats
    int2*  csr  = (int2*)(bufA + (size_t)N_NODES * HIDDEN); // E int2
    int*   bcnt   = (int*)(csr + N_EDGES);                  // NBKT
    int*   boff   = bcnt + NBKT;                            // NBKT+1
    int*   bktCur = boff + NBKT + 1;                        // NBKT
    int*   off    = bktCur + NBKT;                          // N+1
    float* dinv   = (float*)(off + N_NODES + 1);            // N
    int2*  barr   = (int2*)bufA;                            // aliases bufA (dead until agg1)

    const int NT = 256;
    const int blkW = (N_NODES * 64 + NT - 1) / NT;          // wave per node
    const int blkG = (N_NODES + 63) / 64;

    // ---- CSR build (bucketed, locality-preserving) ----
    zero_int_kernel<<<(NBKT + NT - 1) / NT, NT, 0, stream>>>(bcnt, NBKT);
    hist_kernel<<<NBLK_E, NT, 0, stream>>>(dst, bcnt, N_EDGES);
    scan_buckets_kernel<<<1, 1024, 0, stream>>>(bcnt, boff, bktCur);
    bucket_scatter_kernel<<<NBLK_E, NT, 0, stream>>>(src, dst, ew, bktCur, barr, N_EDGES);
    finalize_kernel<<<NBKT, NT, 0, stream>>>(barr, boff, csr, off, dinv);

    // ---- conv1 ----
    gemm64_kernel<<<blkG, NT, 0, stream>>>(nullptr, labels, emb, W1, bufH, N_NODES);
    agg_csr_kernel<<<blkW, NT, 0, stream>>>(bufH, csr, off, dinv, b1, bufA, N_NODES);

    // ---- conv2 ----
    gemm64_kernel<<<blkG, NT, 0, stream>>>(bufA, nullptr, nullptr, W2, bufH, N_NODES);
    agg_csr_kernel<<<blkW, NT, 0, stream>>>(bufH, csr, off, dinv, b2, bufA, N_NODES);

    // ---- fused mean-pool + head ----
    pool_head_kernel<<<NUM_GRAPHS, NT, 0, stream>>>(bufA, batch, W3, b3, W4, b4, out);
}

// Round 5
// 513.163 us; speedup vs baseline: 12.2253x; 1.0771x over previous
//
#include <hip/hip_runtime.h>

#define N_NODES    100000
#define N_EDGES    3200000
#define HIDDEN     64
#define NUM_GRAPHS 128

#define BKT_SHIFT  7
#define NPB        128                              // nodes per bucket
#define NBKT       ((N_NODES + NPB - 1) / NPB)      // 782
#define CHUNK      8192
#define NBLK_E     ((N_EDGES + CHUNK - 1) / CHUNK)  // 391
#define ENTCAP     5632                             // LDS staging capacity (45 KB)

// ---------------- zero int fill ----------------
__global__ void zero_int_kernel(int* __restrict__ p, int n) {
    int i = blockIdx.x * blockDim.x + threadIdx.x;
    if (i < n) p[i] = 0;
}

// ---------------- K1: bucket histogram ----------------
__global__ __launch_bounds__(256) void hist_kernel(const int* __restrict__ dst,
                                                   int* __restrict__ bcnt, int E) {
    __shared__ int h[NBKT];
    int t = threadIdx.x;
    for (int b = t; b < NBKT; b += 256) h[b] = 0;
    __syncthreads();
    int base = blockIdx.x * CHUNK;
    int end  = min(base + CHUNK, E);
    for (int i = base + t; i < end; i += 256)
        atomicAdd(&h[dst[i] >> BKT_SHIFT], 1);
    __syncthreads();
    for (int b = t; b < NBKT; b += 256) {
        int c = h[b];
        if (c) atomicAdd(&bcnt[b], c);
    }
}

// ---------------- K2: scan bucket counts -> bucket offsets + cursors ----------------
__global__ __launch_bounds__(1024) void scan_buckets_kernel(const int* __restrict__ bcnt,
                                                            int* __restrict__ boff,
                                                            int* __restrict__ bktCur) {
    __shared__ int a[1024], b[1024];
    int t = threadIdx.x;
    int v = (t < NBKT) ? bcnt[t] : 0;
    a[t] = v; __syncthreads();
    int* pa = a; int* pb = b;
    #pragma unroll
    for (int d = 1; d < 1024; d <<= 1) {
        int x = pa[t];
        if (t >= d) x += pa[t - d];
        pb[t] = x; __syncthreads();
        int* tmp = pa; pa = pb; pb = tmp;
    }
    int ex = (t == 0) ? 0 : pa[t - 1];
    if (t < NBKT) { boff[t] = ex; bktCur[t] = ex; }
    if (t == NBKT - 1) boff[NBKT] = pa[t];
}

// ---------------- K3: scatter edges into bucket-contiguous buffer ----------------
// entry: x = src | (dstoff << 20), y = bits(ew)
__global__ __launch_bounds__(256) void bucket_scatter_kernel(
    const int* __restrict__ src, const int* __restrict__ dst,
    const float* __restrict__ ew, int* __restrict__ bktCur,
    int2* __restrict__ barr, int E) {
    __shared__ int h[NBKT];
    __shared__ int wbase[NBKT];
    int t = threadIdx.x;
    for (int b = t; b < NBKT; b += 256) h[b] = 0;
    __syncthreads();
    int base = blockIdx.x * CHUNK;
    int end  = min(base + CHUNK, E);
    for (int i = base + t; i < end; i += 256)
        atomicAdd(&h[dst[i] >> BKT_SHIFT], 1);
    __syncthreads();
    for (int b = t; b < NBKT; b += 256) {
        int c = h[b];
        wbase[b] = c ? atomicAdd(&bktCur[b], c) : 0;
    }
    __syncthreads();
    for (int b = t; b < NBKT; b += 256) h[b] = 0;
    __syncthreads();
    for (int i = base + t; i < end; i += 256) {
        int d = dst[i];
        int bk = d >> BKT_SHIFT;
        int p = atomicAdd(&h[bk], 1);
        barr[wbase[bk] + p] = make_int2(src[i] | ((d & (NPB - 1)) << 20),
                                        __float_as_int(ew[i]));
    }
}

// ---------------- K4: per-bucket finalize -> CSR + off + dinv ----------------
__global__ __launch_bounds__(256) void finalize_kernel(
    const int2* __restrict__ barr, const int* __restrict__ boff,
    int2* __restrict__ csr, int* __restrict__ off, float* __restrict__ dinv) {
    __shared__ int2  ent[ENTCAP];
    __shared__ int   hcnt[NPB];
    __shared__ float wsum[NPB];
    __shared__ int   ha[NPB], hcur[NPB];
    int b = blockIdx.x;
    int t = threadIdx.x;
    int s = boff[b], e = boff[b + 1];
    int m = e - s;
    int node0 = b << BKT_SHIFT;
    int nn = min(NPB, N_NODES - node0);
    if (t < NPB) { hcnt[t] = 0; wsum[t] = 0.f; }
    __syncthreads();
    bool staged = (m <= ENTCAP);
    for (int i = t; i < m; i += 256) {
        int2 v = barr[s + i];
        if (staged) ent[i] = v;
        int doff = (v.x >> 20) & (NPB - 1);
        atomicAdd(&hcnt[doff], 1);
        atomicAdd(&wsum[doff], __int_as_float(v.y));
    }
    __syncthreads();
    if (t < NPB) ha[t] = hcnt[t];
    __syncthreads();
    #pragma unroll
    for (int d = 1; d < NPB; d <<= 1) {
        int x = 0;
        if (t < NPB) { x = ha[t]; if (t >= d) x += ha[t - d]; }
        __syncthreads();
        if (t < NPB) ha[t] = x;
        __syncthreads();
    }
    if (t < NPB) {
        int ex = (t == 0) ? 0 : ha[t - 1];
        hcur[t] = s + ex;
        if (t < nn) {
            off[node0 + t]  = s + ex;
            dinv[node0 + t] = rsqrtf(wsum[t] + 1.0f);
        }
    }
    if (b == NBKT - 1 && t == 0) off[N_NODES] = e;
    __syncthreads();
    for (int i = t; i < m; i += 256) {
        int2 v = staged ? ent[i] : barr[s + i];
        int doff = (v.x >> 20) & (NPB - 1);
        int p = atomicAdd(&hcur[doff], 1);
        csr[p] = make_int2(v.x & 0xFFFFF, v.y);
    }
}

// ---------------- pull aggregation in x-space (before GEMM) ----------------
// OUT[i] = dinv[i] * (sum_e ew*dinv[src]*x[src]) + dinv[i]^2 * x[i]
// x[r] = labels ? emb[labels[r]] : X[r]
__global__ __launch_bounds__(256) void agg_pull_kernel(
    const float* __restrict__ X, const int* __restrict__ labels,
    const float* __restrict__ emb,
    const int2* __restrict__ csr, const int* __restrict__ off,
    const float* __restrict__ dinv, float* __restrict__ OUT, int n) {
    int wid  = (blockIdx.x * blockDim.x + threadIdx.x) >> 6;
    if (wid >= n) return;
    int lane = threadIdx.x & 63;
    int q = lane & 15, g = lane >> 4;
    int i   = off[wid] + g;
    int end = off[wid + 1];
    float4 acc = make_float4(0.f, 0.f, 0.f, 0.f);
    // 2-deep software pipeline: entries and row loads both prefetched
    int2 e0 = (i     < end) ? csr[i]     : make_int2(0, 0);
    int2 e1 = (i + 4 < end) ? csr[i + 4] : make_int2(0, 0);
    int s0 = e0.x;
    const float4* rp0 = (const float4*)(labels ? emb + (size_t)labels[s0] * HIDDEN
                                               : X   + (size_t)s0 * HIDDEN);
    float  w0 = __int_as_float(e0.y) * dinv[s0];
    float4 h0 = rp0[q];
    while (i < end) {
        int2 e2 = (i + 8 < end) ? csr[i + 8] : make_int2(0, 0);
        int s1 = e1.x;
        const float4* rp1 = (const float4*)(labels ? emb + (size_t)labels[s1] * HIDDEN
                                                   : X   + (size_t)s1 * HIDDEN);
        float  w1 = __int_as_float(e1.y) * dinv[s1];
        float4 h1 = rp1[q];
        acc.x = fmaf(h0.x, w0, acc.x);
        acc.y = fmaf(h0.y, w0, acc.y);
        acc.z = fmaf(h0.z, w0, acc.z);
        acc.w = fmaf(h0.w, w0, acc.w);
        w0 = w1; h0 = h1; e1 = e2;
        i += 4;
    }
    acc.x += __shfl_xor(acc.x, 16, 64); acc.y += __shfl_xor(acc.y, 16, 64);
    acc.z += __shfl_xor(acc.z, 16, 64); acc.w += __shfl_xor(acc.w, 16, 64);
    acc.x += __shfl_xor(acc.x, 32, 64); acc.y += __shfl_xor(acc.y, 32, 64);
    acc.z += __shfl_xor(acc.z, 32, 64); acc.w += __shfl_xor(acc.w, 32, 64);
    if (g == 0) {
        float di  = dinv[wid];
        float di2 = di * di;
        const float4* xr = (const float4*)(labels ? emb + (size_t)labels[wid] * HIDDEN
                                                  : X   + (size_t)wid * HIDDEN);
        float4 xv = xr[q];
        float4 v;
        v.x = fmaf(acc.x, di, xv.x * di2);
        v.y = fmaf(acc.y, di, xv.y * di2);
        v.z = fmaf(acc.z, di, xv.z * di2);
        v.w = fmaf(acc.w, di, xv.w * di2);
        *(float4*)(OUT + (size_t)wid * HIDDEN + q * 4) = v;
    }
}

// ---------------- GEMM + bias + relu; optionally fused mean-pool accumulation ----------------
__global__ __launch_bounds__(256) void gemm64_kernel(
    const float* __restrict__ X, const float* __restrict__ W,
    const float* __restrict__ bias, float* __restrict__ OUT,
    const int* __restrict__ batch, float* __restrict__ gsum,
    int do_pool, int n) {
    __shared__ float Ws[64 * 64];
    __shared__ float Xs[64 * 65];
    int t = threadIdx.x;
    #pragma unroll
    for (int s = 0; s < 16; ++s) Ws[s * 256 + t] = W[s * 256 + t];
    int r0   = blockIdx.x * 64;
    int lrow = t >> 2;
    int c0   = (t & 3) * 16;
    int grow = r0 + lrow;
    const float* srcrow = (grow < n) ? (X + (size_t)grow * HIDDEN) : X;
    #pragma unroll
    for (int c = 0; c < 16; c += 4) {
        float4 v = *(const float4*)(srcrow + c0 + c);
        Xs[lrow * 65 + c0 + c + 0] = v.x;
        Xs[lrow * 65 + c0 + c + 1] = v.y;
        Xs[lrow * 65 + c0 + c + 2] = v.z;
        Xs[lrow * 65 + c0 + c + 3] = v.w;
    }
    __syncthreads();
    int row = t & 63;
    int j0  = (t >> 6) * 16;
    float4 a0 = *(const float4*)(bias + j0 + 0);
    float4 a1 = *(const float4*)(bias + j0 + 4);
    float4 a2 = *(const float4*)(bias + j0 + 8);
    float4 a3 = *(const float4*)(bias + j0 + 12);
    #pragma unroll
    for (int k = 0; k < 64; ++k) {
        float xv = Xs[row * 65 + k];
        const float4* wr = (const float4*)(Ws + k * 64 + j0);
        float4 w0 = wr[0], w1 = wr[1], w2 = wr[2], w3 = wr[3];
        a0.x = fmaf(xv, w0.x, a0.x); a0.y = fmaf(xv, w0.y, a0.y);
        a0.z = fmaf(xv, w0.z, a0.z); a0.w = fmaf(xv, w0.w, a0.w);
        a1.x = fmaf(xv, w1.x, a1.x); a1.y = fmaf(xv, w1.y, a1.y);
        a1.z = fmaf(xv, w1.z, a1.z); a1.w = fmaf(xv, w1.w, a1.w);
        a2.x = fmaf(xv, w2.x, a2.x); a2.y = fmaf(xv, w2.y, a2.y);
        a2.z = fmaf(xv, w2.z, a2.z); a2.w = fmaf(xv, w2.w, a2.w);
        a3.x = fmaf(xv, w3.x, a3.x); a3.y = fmaf(xv, w3.y, a3.y);
        a3.z = fmaf(xv, w3.z, a3.z); a3.w = fmaf(xv, w3.w, a3.w);
    }
    // relu
    a0.x = fmaxf(a0.x, 0.f); a0.y = fmaxf(a0.y, 0.f); a0.z = fmaxf(a0.z, 0.f); a0.w = fmaxf(a0.w, 0.f);
    a1.x = fmaxf(a1.x, 0.f); a1.y = fmaxf(a1.y, 0.f); a1.z = fmaxf(a1.z, 0.f); a1.w = fmaxf(a1.w, 0.f);
    a2.x = fmaxf(a2.x, 0.f); a2.y = fmaxf(a2.y, 0.f); a2.z = fmaxf(a2.z, 0.f); a2.w = fmaxf(a2.w, 0.f);
    a3.x = fmaxf(a3.x, 0.f); a3.y = fmaxf(a3.y, 0.f); a3.z = fmaxf(a3.z, 0.f); a3.w = fmaxf(a3.w, 0.f);
    int gr = r0 + row;
    if (!do_pool) {
        if (gr < n) {
            float4* o = (float4*)(OUT + (size_t)gr * HIDDEN + j0);
            o[0] = a0; o[1] = a1; o[2] = a2; o[3] = a3;
        }
    } else {
        bool valid = (gr < n);
        int brow  = valid ? batch[gr] : 0x7fffffff;   // min identity
        int bmaxv = valid ? brow      : -1;           // max identity
        int gmin = brow, gmax = bmaxv;
        #pragma unroll
        for (int o = 1; o < 64; o <<= 1) {
            gmin = min(gmin, __shfl_xor(gmin, o, 64));
            gmax = max(gmax, __shfl_xor(gmax, o, 64));
        }
        const float4 z = make_float4(0.f, 0.f, 0.f, 0.f);
        for (int gg = gmin; gg <= gmax; ++gg) {
            bool m = (brow == gg);
            float4 v0 = m ? a0 : z, v1 = m ? a1 : z, v2 = m ? a2 : z, v3 = m ? a3 : z;
            #pragma unroll
            for (int o = 1; o < 64; o <<= 1) {
                v0.x += __shfl_xor(v0.x, o, 64); v0.y += __shfl_xor(v0.y, o, 64);
                v0.z += __shfl_xor(v0.z, o, 64); v0.w += __shfl_xor(v0.w, o, 64);
                v1.x += __shfl_xor(v1.x, o, 64); v1.y += __shfl_xor(v1.y, o, 64);
                v1.z += __shfl_xor(v1.z, o, 64); v1.w += __shfl_xor(v1.w, o, 64);
                v2.x += __shfl_xor(v2.x, o, 64); v2.y += __shfl_xor(v2.y, o, 64);
                v2.z += __shfl_xor(v2.z, o, 64); v2.w += __shfl_xor(v2.w, o, 64);
                v3.x += __shfl_xor(v3.x, o, 64); v3.y += __shfl_xor(v3.y, o, 64);
                v3.z += __shfl_xor(v3.z, o, 64); v3.w += __shfl_xor(v3.w, o, 64);
            }
            if (row == 0) {
                float* gp = gsum + (size_t)gg * HIDDEN + j0;
                atomicAdd(gp + 0,  v0.x); atomicAdd(gp + 1,  v0.y);
                atomicAdd(gp + 2,  v0.z); atomicAdd(gp + 3,  v0.w);
                atomicAdd(gp + 4,  v1.x); atomicAdd(gp + 5,  v1.y);
                atomicAdd(gp + 6,  v1.z); atomicAdd(gp + 7,  v1.w);
                atomicAdd(gp + 8,  v2.x); atomicAdd(gp + 9,  v2.y);
                atomicAdd(gp + 10, v2.z); atomicAdd(gp + 11, v2.w);
                atomicAdd(gp + 12, v3.x); atomicAdd(gp + 13, v3.y);
                atomicAdd(gp + 14, v3.z); atomicAdd(gp + 15, v3.w);
            }
        }
    }
}

// ---------------- head: mean -> relu(g@W3+b3) -> @W4+b4 ----------------
__global__ __launch_bounds__(64) void head_kernel(
    const float* __restrict__ gsum, const int* __restrict__ batch,
    const float* __restrict__ W3, const float* __restrict__ b3,
    const float* __restrict__ W4, const float* __restrict__ b4,
    float* __restrict__ out) {
    __shared__ int   sb[2];
    __shared__ float gv[64];
    int gidx = blockIdx.x;
    int t = threadIdx.x;
    if (t < 2) {
        int target = gidx + t;
        int lo = 0, hi = N_NODES;
        while (lo < hi) {
            int mid = (lo + hi) >> 1;
            if (batch[mid] < target) lo = mid + 1; else hi = mid;
        }
        sb[t] = lo;
    }
    __syncthreads();
    float cnt = (float)(sb[1] - sb[0]);
    gv[t] = gsum[gidx * 64 + t] / fmaxf(cnt, 1.0f);
    __syncthreads();
    float acc = b3[t];
    #pragma unroll
    for (int k = 0; k < 64; ++k) acc = fmaf(gv[k], W3[k * 64 + t], acc);
    float p = fmaxf(acc, 0.f) * W4[t];
    #pragma unroll
    for (int o = 32; o > 0; o >>= 1) p += __shfl_down(p, o, 64);
    if (t == 0) out[gidx] = p + b4[0];
}

extern "C" void kernel_launch(void* const* d_in, const int* in_sizes, int n_in,
                              void* d_out, int out_size, void* d_ws, size_t ws_size,
                              hipStream_t stream) {
    const int*   labels = (const int*)d_in[0];
    const int*   ei     = (const int*)d_in[1];
    const int*   src    = ei;
    const int*   dst    = ei + N_EDGES;
    const float* ew     = (const float*)d_in[2];
    const int*   batch  = (const int*)d_in[3];
    const float* emb    = (const float*)d_in[4];
    const float* W1 = (const float*)d_in[5],  *b1 = (const float*)d_in[6];
    const float* W2 = (const float*)d_in[7],  *b2 = (const float*)d_in[8];
    const float* W3 = (const float*)d_in[9],  *b3 = (const float*)d_in[10];
    const float* W4 = (const float*)d_in[11], *b4 = (const float*)d_in[12];
    float* out = (float*)d_out;

    // workspace carve
    float* ws   = (float*)d_ws;
    float* bufH = ws;                                       // N*64 floats
    float* bufA = bufH + (size_t)N_NODES * HIDDEN;          // N*64 floats
    int2*  csr  = (int2*)(bufA + (size_t)N_NODES * HIDDEN); // E int2
    int*   bcnt   = (int*)(csr + N_EDGES);                  // NBKT
    int*   boff   = bcnt + NBKT;                            // NBKT+1
    int*   bktCur = boff + NBKT + 1;                        // NBKT
    int*   off    = bktCur + NBKT;                          // N+1
    float* dinv   = (float*)(off + N_NODES + 1);            // N
    float* gsum   = dinv + N_NODES;                         // 128*64
    int2*  barr   = (int2*)bufA;                            // aliases bufA (dead until gemm1)

    const int NT = 256;
    const int blkW = (N_NODES * 64 + NT - 1) / NT;          // wave per node
    const int blkG = (N_NODES + 63) / 64;

    // ---- CSR build ----
    zero_int_kernel<<<(NBKT + NT - 1) / NT, NT, 0, stream>>>(bcnt, NBKT);
    hist_kernel<<<NBLK_E, NT, 0, stream>>>(dst, bcnt, N_EDGES);
    scan_buckets_kernel<<<1, 1024, 0, stream>>>(bcnt, boff, bktCur);
    bucket_scatter_kernel<<<NBLK_E, NT, 0, stream>>>(src, dst, ew, bktCur, barr, N_EDGES);
    finalize_kernel<<<NBKT, NT, 0, stream>>>(barr, boff, csr, off, dinv);
    zero_int_kernel<<<(NUM_GRAPHS * 64 + NT - 1) / NT, NT, 0, stream>>>((int*)gsum, NUM_GRAPHS * 64);

    // ---- conv1: aggregate in emb-space (L2-resident gather), then GEMM ----
    agg_pull_kernel<<<blkW, NT, 0, stream>>>(nullptr, labels, emb, csr, off, dinv, bufH, N_NODES);
    gemm64_kernel<<<blkG, NT, 0, stream>>>(bufH, W1, b1, bufA, nullptr, nullptr, 0, N_NODES);

    // ---- conv2: aggregate OUT1, then GEMM fused with mean-pool ----
    agg_pull_kernel<<<blkW, NT, 0, stream>>>(bufA, nullptr, nullptr, csr, off, dinv, bufH, N_NODES);
    gemm64_kernel<<<blkG, NT, 0, stream>>>(bufH, W2, b2, nullptr, batch, gsum, 1, N_NODES);

    // ---- head ----
    head_kernel<<<NUM_GRAPHS, 64, 0, stream>>>(gsum, batch, W3, b3, W4, b4, out);
}

// Round 6
// 465.120 us; speedup vs baseline: 13.4881x; 1.1033x over previous
//
#include <hip/hip_runtime.h>
#include <hip/hip_fp16.h>

#define N_NODES    100000
#define N_EDGES    3200000
#define HIDDEN     64
#define NUM_GRAPHS 128

#define BKT_SHIFT  7
#define NPB        128                              // nodes per bucket
#define NBKT       ((N_NODES + NPB - 1) / NPB)      // 782
#define CHUNK      8192
#define NBLK_E     ((N_EDGES + CHUNK - 1) / CHUNK)  // 391
#define ENTCAP     5632                             // LDS staging capacity (45 KB)

// ---------------- zero int fill ----------------
__global__ void zero_int_kernel(int* __restrict__ p, int n) {
    int i = blockIdx.x * blockDim.x + threadIdx.x;
    if (i < n) p[i] = 0;
}

// ---------------- K1: bucket histogram ----------------
__global__ __launch_bounds__(256) void hist_kernel(const int* __restrict__ dst,
                                                   int* __restrict__ bcnt, int E) {
    __shared__ int h[NBKT];
    int t = threadIdx.x;
    for (int b = t; b < NBKT; b += 256) h[b] = 0;
    __syncthreads();
    int base = blockIdx.x * CHUNK;
    int end  = min(base + CHUNK, E);
    for (int i = base + t; i < end; i += 256)
        atomicAdd(&h[dst[i] >> BKT_SHIFT], 1);
    __syncthreads();
    for (int b = t; b < NBKT; b += 256) {
        int c = h[b];
        if (c) atomicAdd(&bcnt[b], c);
    }
}

// ---------------- K2: scan bucket counts -> offsets + cursors; also zero gsum ----------------
__global__ __launch_bounds__(1024) void scan_buckets_kernel(const int* __restrict__ bcnt,
                                                            int* __restrict__ boff,
                                                            int* __restrict__ bktCur,
                                                            float* __restrict__ gsum) {
    __shared__ int a[1024], b[1024];
    int t = threadIdx.x;
    for (int k = t; k < NUM_GRAPHS * 64; k += 1024) gsum[k] = 0.f;
    int v = (t < NBKT) ? bcnt[t] : 0;
    a[t] = v; __syncthreads();
    int* pa = a; int* pb = b;
    #pragma unroll
    for (int d = 1; d < 1024; d <<= 1) {
        int x = pa[t];
        if (t >= d) x += pa[t - d];
        pb[t] = x; __syncthreads();
        int* tmp = pa; pa = pb; pb = tmp;
    }
    int ex = (t == 0) ? 0 : pa[t - 1];
    if (t < NBKT) { boff[t] = ex; bktCur[t] = ex; }
    if (t == NBKT - 1) boff[NBKT] = pa[t];
}

// ---------------- K3: scatter edges into bucket-contiguous buffer ----------------
// entry: x = src | (dstoff << 20), y = bits(ew)
__global__ __launch_bounds__(256) void bucket_scatter_kernel(
    const int* __restrict__ src, const int* __restrict__ dst,
    const float* __restrict__ ew, int* __restrict__ bktCur,
    int2* __restrict__ barr, int E) {
    __shared__ int h[NBKT];
    __shared__ int wbase[NBKT];
    int t = threadIdx.x;
    for (int b = t; b < NBKT; b += 256) h[b] = 0;
    __syncthreads();
    int base = blockIdx.x * CHUNK;
    int end  = min(base + CHUNK, E);
    for (int i = base + t; i < end; i += 256)
        atomicAdd(&h[dst[i] >> BKT_SHIFT], 1);
    __syncthreads();
    for (int b = t; b < NBKT; b += 256) {
        int c = h[b];
        wbase[b] = c ? atomicAdd(&bktCur[b], c) : 0;
    }
    __syncthreads();
    for (int b = t; b < NBKT; b += 256) h[b] = 0;
    __syncthreads();
    for (int i = base + t; i < end; i += 256) {
        int d = dst[i];
        int bk = d >> BKT_SHIFT;
        int p = atomicAdd(&h[bk], 1);
        barr[wbase[bk] + p] = make_int2(src[i] | ((d & (NPB - 1)) << 20),
                                        __float_as_int(ew[i]));
    }
}

// ---------------- K4: per-bucket finalize -> CSR (weight pre-folded with dinv[dst]) ----------------
__global__ __launch_bounds__(256) void finalize_kernel(
    const int2* __restrict__ barr, const int* __restrict__ boff,
    int2* __restrict__ csr, int* __restrict__ off, float* __restrict__ dinv) {
    __shared__ int2  ent[ENTCAP];
    __shared__ int   hcnt[NPB];
    __shared__ float wsum[NPB];
    __shared__ float ldv[NPB];
    __shared__ int   ha[NPB], hcur[NPB];
    int b = blockIdx.x;
    int t = threadIdx.x;
    int s = boff[b], e = boff[b + 1];
    int m = e - s;
    int node0 = b << BKT_SHIFT;
    int nn = min(NPB, N_NODES - node0);
    if (t < NPB) { hcnt[t] = 0; wsum[t] = 0.f; }
    __syncthreads();
    bool staged = (m <= ENTCAP);
    for (int i = t; i < m; i += 256) {
        int2 v = barr[s + i];
        if (staged) ent[i] = v;
        int doff = (v.x >> 20) & (NPB - 1);
        atomicAdd(&hcnt[doff], 1);
        atomicAdd(&wsum[doff], __int_as_float(v.y));
    }
    __syncthreads();
    if (t < NPB) ha[t] = hcnt[t];
    __syncthreads();
    #pragma unroll
    for (int d = 1; d < NPB; d <<= 1) {
        int x = 0;
        if (t < NPB) { x = ha[t]; if (t >= d) x += ha[t - d]; }
        __syncthreads();
        if (t < NPB) ha[t] = x;
        __syncthreads();
    }
    if (t < NPB) {
        int ex = (t == 0) ? 0 : ha[t - 1];
        hcur[t] = s + ex;
        float dv = rsqrtf(wsum[t] + 1.0f);
        ldv[t] = dv;
        if (t < nn) {
            off[node0 + t]  = s + ex;
            dinv[node0 + t] = dv;
        }
    }
    if (b == NBKT - 1 && t == 0) off[N_NODES] = e;
    __syncthreads();
    for (int i = t; i < m; i += 256) {
        int2 v = staged ? ent[i] : barr[s + i];
        int doff = (v.x >> 20) & (NPB - 1);
        int p = atomicAdd(&hcur[doff], 1);
        // fold dinv[dst] into stored edge weight
        float wfold = __int_as_float(v.y) * ldv[doff];
        csr[p] = make_int2(v.x & 0xFFFFF, __float_as_int(wfold));
    }
}

// ---------------- conv1 pull aggregation (fp32 emb via labels) ----------------
// OUT[i] = sum_e (ew*dinv[d])*dinv[src]*x[src] + dinv[i]^2 * x[i],  x[r]=emb[labels[r]]
__global__ __launch_bounds__(256) void agg_pull1_kernel(
    const int* __restrict__ labels, const float* __restrict__ emb,
    const int2* __restrict__ csr, const int* __restrict__ off,
    const float* __restrict__ dinv, float* __restrict__ OUT, int n) {
    int wid  = (blockIdx.x * blockDim.x + threadIdx.x) >> 6;
    if (wid >= n) return;
    int lane = threadIdx.x & 63;
    int q = lane & 15, g = lane >> 4;
    int i   = off[wid] + g;
    int end = off[wid + 1];
    float4 acc = make_float4(0.f, 0.f, 0.f, 0.f);
    int2 e0 = (i     < end) ? csr[i]     : make_int2(0, 0);
    int2 e1 = (i + 4 < end) ? csr[i + 4] : make_int2(0, 0);
    int s0 = e0.x;
    const float4* rp0 = (const float4*)(emb + (size_t)labels[s0] * HIDDEN);
    float  w0 = __int_as_float(e0.y) * dinv[s0];
    float4 h0 = rp0[q];
    while (i < end) {
        int2 e2 = (i + 8 < end) ? csr[i + 8] : make_int2(0, 0);
        int s1 = e1.x;
        const float4* rp1 = (const float4*)(emb + (size_t)labels[s1] * HIDDEN);
        float  w1 = __int_as_float(e1.y) * dinv[s1];
        float4 h1 = rp1[q];
        acc.x = fmaf(h0.x, w0, acc.x);
        acc.y = fmaf(h0.y, w0, acc.y);
        acc.z = fmaf(h0.z, w0, acc.z);
        acc.w = fmaf(h0.w, w0, acc.w);
        w0 = w1; h0 = h1; e1 = e2;
        i += 4;
    }
    acc.x += __shfl_xor(acc.x, 16, 64); acc.y += __shfl_xor(acc.y, 16, 64);
    acc.z += __shfl_xor(acc.z, 16, 64); acc.w += __shfl_xor(acc.w, 16, 64);
    acc.x += __shfl_xor(acc.x, 32, 64); acc.y += __shfl_xor(acc.y, 32, 64);
    acc.z += __shfl_xor(acc.z, 32, 64); acc.w += __shfl_xor(acc.w, 32, 64);
    if (g == 0) {
        float di  = dinv[wid];
        float di2 = di * di;
        const float4* xr = (const float4*)(emb + (size_t)labels[wid] * HIDDEN);
        float4 xv = xr[q];
        float4 v;
        v.x = fmaf(xv.x, di2, acc.x);
        v.y = fmaf(xv.y, di2, acc.y);
        v.z = fmaf(xv.z, di2, acc.z);
        v.w = fmaf(xv.w, di2, acc.w);
        *(float4*)(OUT + (size_t)wid * HIDDEN + q * 4) = v;
    }
}

// ---------------- conv2 pull aggregation (fp16 activation gather) ----------------
__global__ __launch_bounds__(256) void agg_pull2_kernel(
    const __half* __restrict__ Xh,
    const int2* __restrict__ csr, const int* __restrict__ off,
    const float* __restrict__ dinv, float* __restrict__ OUT, int n) {
    int wid  = (blockIdx.x * blockDim.x + threadIdx.x) >> 6;
    if (wid >= n) return;
    int lane = threadIdx.x & 63;
    int q = lane & 15, g = lane >> 4;
    int i   = off[wid] + g;
    int end = off[wid + 1];
    float4 acc = make_float4(0.f, 0.f, 0.f, 0.f);
    int2 e0 = (i     < end) ? csr[i]     : make_int2(0, 0);
    int2 e1 = (i + 4 < end) ? csr[i + 4] : make_int2(0, 0);
    int s0 = e0.x;
    uint2  r0 = *(const uint2*)(Xh + (size_t)s0 * HIDDEN + q * 4);
    float  w0 = __int_as_float(e0.y) * dinv[s0];
    while (i < end) {
        int2 e2 = (i + 8 < end) ? csr[i + 8] : make_int2(0, 0);
        int s1 = e1.x;
        uint2  r1 = *(const uint2*)(Xh + (size_t)s1 * HIDDEN + q * 4);
        float  w1 = __int_as_float(e1.y) * dinv[s1];
        const __half2* hp = (const __half2*)&r0;
        float2 f01 = __half22float2(hp[0]);
        float2 f23 = __half22float2(hp[1]);
        acc.x = fmaf(f01.x, w0, acc.x);
        acc.y = fmaf(f01.y, w0, acc.y);
        acc.z = fmaf(f23.x, w0, acc.z);
        acc.w = fmaf(f23.y, w0, acc.w);
        w0 = w1; r0 = r1; e1 = e2;
        i += 4;
    }
    acc.x += __shfl_xor(acc.x, 16, 64); acc.y += __shfl_xor(acc.y, 16, 64);
    acc.z += __shfl_xor(acc.z, 16, 64); acc.w += __shfl_xor(acc.w, 16, 64);
    acc.x += __shfl_xor(acc.x, 32, 64); acc.y += __shfl_xor(acc.y, 32, 64);
    acc.z += __shfl_xor(acc.z, 32, 64); acc.w += __shfl_xor(acc.w, 32, 64);
    if (g == 0) {
        float di  = dinv[wid];
        float di2 = di * di;
        uint2 xu = *(const uint2*)(Xh + (size_t)wid * HIDDEN + q * 4);
        const __half2* xp = (const __half2*)&xu;
        float2 x01 = __half22float2(xp[0]);
        float2 x23 = __half22float2(xp[1]);
        float4 v;
        v.x = fmaf(x01.x, di2, acc.x);
        v.y = fmaf(x01.y, di2, acc.y);
        v.z = fmaf(x23.x, di2, acc.z);
        v.w = fmaf(x23.y, di2, acc.w);
        *(float4*)(OUT + (size_t)wid * HIDDEN + q * 4) = v;
    }
}

// ---------------- GEMM + bias + relu; out fp16 (mode 0) or fused mean-pool (mode 1) ----------------
__global__ __launch_bounds__(256) void gemm64_kernel(
    const float* __restrict__ X, const float* __restrict__ W,
    const float* __restrict__ bias, __half* __restrict__ OUTH,
    const int* __restrict__ batch, float* __restrict__ gsum,
    int do_pool, int n) {
    __shared__ float Ws[64 * 64];
    __shared__ float Xs[64 * 65];
    int t = threadIdx.x;
    #pragma unroll
    for (int s = 0; s < 16; ++s) Ws[s * 256 + t] = W[s * 256 + t];
    int r0   = blockIdx.x * 64;
    int lrow = t >> 2;
    int c0   = (t & 3) * 16;
    int grow = r0 + lrow;
    const float* srcrow = (grow < n) ? (X + (size_t)grow * HIDDEN) : X;
    #pragma unroll
    for (int c = 0; c < 16; c += 4) {
        float4 v = *(const float4*)(srcrow + c0 + c);
        Xs[lrow * 65 + c0 + c + 0] = v.x;
        Xs[lrow * 65 + c0 + c + 1] = v.y;
        Xs[lrow * 65 + c0 + c + 2] = v.z;
        Xs[lrow * 65 + c0 + c + 3] = v.w;
    }
    __syncthreads();
    int row = t & 63;
    int j0  = (t >> 6) * 16;
    float4 a0 = *(const float4*)(bias + j0 + 0);
    float4 a1 = *(const float4*)(bias + j0 + 4);
    float4 a2 = *(const float4*)(bias + j0 + 8);
    float4 a3 = *(const float4*)(bias + j0 + 12);
    #pragma unroll
    for (int k = 0; k < 64; ++k) {
        float xv = Xs[row * 65 + k];
        const float4* wr = (const float4*)(Ws + k * 64 + j0);
        float4 w0 = wr[0], w1 = wr[1], w2 = wr[2], w3 = wr[3];
        a0.x = fmaf(xv, w0.x, a0.x); a0.y = fmaf(xv, w0.y, a0.y);
        a0.z = fmaf(xv, w0.z, a0.z); a0.w = fmaf(xv, w0.w, a0.w);
        a1.x = fmaf(xv, w1.x, a1.x); a1.y = fmaf(xv, w1.y, a1.y);
        a1.z = fmaf(xv, w1.z, a1.z); a1.w = fmaf(xv, w1.w, a1.w);
        a2.x = fmaf(xv, w2.x, a2.x); a2.y = fmaf(xv, w2.y, a2.y);
        a2.z = fmaf(xv, w2.z, a2.z); a2.w = fmaf(xv, w2.w, a2.w);
        a3.x = fmaf(xv, w3.x, a3.x); a3.y = fmaf(xv, w3.y, a3.y);
        a3.z = fmaf(xv, w3.z, a3.z); a3.w = fmaf(xv, w3.w, a3.w);
    }
    // relu
    a0.x = fmaxf(a0.x, 0.f); a0.y = fmaxf(a0.y, 0.f); a0.z = fmaxf(a0.z, 0.f); a0.w = fmaxf(a0.w, 0.f);
    a1.x = fmaxf(a1.x, 0.f); a1.y = fmaxf(a1.y, 0.f); a1.z = fmaxf(a1.z, 0.f); a1.w = fmaxf(a1.w, 0.f);
    a2.x = fmaxf(a2.x, 0.f); a2.y = fmaxf(a2.y, 0.f); a2.z = fmaxf(a2.z, 0.f); a2.w = fmaxf(a2.w, 0.f);
    a3.x = fmaxf(a3.x, 0.f); a3.y = fmaxf(a3.y, 0.f); a3.z = fmaxf(a3.z, 0.f); a3.w = fmaxf(a3.w, 0.f);
    int gr = r0 + row;
    if (!do_pool) {
        if (gr < n) {
            union { __half2 h2[8]; uint4 u4[2]; } pk;
            pk.h2[0] = __floats2half2_rn(a0.x, a0.y);
            pk.h2[1] = __floats2half2_rn(a0.z, a0.w);
            pk.h2[2] = __floats2half2_rn(a1.x, a1.y);
            pk.h2[3] = __floats2half2_rn(a1.z, a1.w);
            pk.h2[4] = __floats2half2_rn(a2.x, a2.y);
            pk.h2[5] = __floats2half2_rn(a2.z, a2.w);
            pk.h2[6] = __floats2half2_rn(a3.x, a3.y);
            pk.h2[7] = __floats2half2_rn(a3.z, a3.w);
            uint4* o = (uint4*)(OUTH + (size_t)gr * HIDDEN + j0);
            o[0] = pk.u4[0]; o[1] = pk.u4[1];
        }
    } else {
        bool valid = (gr < n);
        int brow  = valid ? batch[gr] : 0x7fffffff;
        int bmaxv = valid ? brow      : -1;
        int gmin = brow, gmax = bmaxv;
        #pragma unroll
        for (int o = 1; o < 64; o <<= 1) {
            gmin = min(gmin, __shfl_xor(gmin, o, 64));
            gmax = max(gmax, __shfl_xor(gmax, o, 64));
        }
        const float4 z = make_float4(0.f, 0.f, 0.f, 0.f);
        for (int gg = gmin; gg <= gmax; ++gg) {
            bool m = (brow == gg);
            float4 v0 = m ? a0 : z, v1 = m ? a1 : z, v2 = m ? a2 : z, v3 = m ? a3 : z;
            #pragma unroll
            for (int o = 1; o < 64; o <<= 1) {
                v0.x += __shfl_xor(v0.x, o, 64); v0.y += __shfl_xor(v0.y, o, 64);
                v0.z += __shfl_xor(v0.z, o, 64); v0.w += __shfl_xor(v0.w, o, 64);
                v1.x += __shfl_xor(v1.x, o, 64); v1.y += __shfl_xor(v1.y, o, 64);
                v1.z += __shfl_xor(v1.z, o, 64); v1.w += __shfl_xor(v1.w, o, 64);
                v2.x += __shfl_xor(v2.x, o, 64); v2.y += __shfl_xor(v2.y, o, 64);
                v2.z += __shfl_xor(v2.z, o, 64); v2.w += __shfl_xor(v2.w, o, 64);
                v3.x += __shfl_xor(v3.x, o, 64); v3.y += __shfl_xor(v3.y, o, 64);
                v3.z += __shfl_xor(v3.z, o, 64); v3.w += __shfl_xor(v3.w, o, 64);
            }
            if (row == 0) {
                float* gp = gsum + (size_t)gg * HIDDEN + j0;
                atomicAdd(gp + 0,  v0.x); atomicAdd(gp + 1,  v0.y);
                atomicAdd(gp + 2,  v0.z); atomicAdd(gp + 3,  v0.w);
                atomicAdd(gp + 4,  v1.x); atomicAdd(gp + 5,  v1.y);
                atomicAdd(gp + 6,  v1.z); atomicAdd(gp + 7,  v1.w);
                atomicAdd(gp + 8,  v2.x); atomicAdd(gp + 9,  v2.y);
                atomicAdd(gp + 10, v2.z); atomicAdd(gp + 11, v2.w);
                atomicAdd(gp + 12, v3.x); atomicAdd(gp + 13, v3.y);
                atomicAdd(gp + 14, v3.z); atomicAdd(gp + 15, v3.w);
            }
        }
    }
}

// ---------------- head: mean -> relu(g@W3+b3) -> @W4+b4 ----------------
__global__ __launch_bounds__(64) void head_kernel(
    const float* __restrict__ gsum, const int* __restrict__ batch,
    const float* __restrict__ W3, const float* __restrict__ b3,
    const float* __restrict__ W4, const float* __restrict__ b4,
    float* __restrict__ out) {
    __shared__ int   sb[2];
    __shared__ float gv[64];
    int gidx = blockIdx.x;
    int t = threadIdx.x;
    if (t < 2) {
        int target = gidx + t;
        int lo = 0, hi = N_NODES;
        while (lo < hi) {
            int mid = (lo + hi) >> 1;
            if (batch[mid] < target) lo = mid + 1; else hi = mid;
        }
        sb[t] = lo;
    }
    __syncthreads();
    float cnt = (float)(sb[1] - sb[0]);
    gv[t] = gsum[gidx * 64 + t] / fmaxf(cnt, 1.0f);
    __syncthreads();
    float acc = b3[t];
    #pragma unroll
    for (int k = 0; k < 64; ++k) acc = fmaf(gv[k], W3[k * 64 + t], acc);
    float p = fmaxf(acc, 0.f) * W4[t];
    #pragma unroll
    for (int o = 32; o > 0; o >>= 1) p += __shfl_down(p, o, 64);
    if (t == 0) out[gidx] = p + b4[0];
}

extern "C" void kernel_launch(void* const* d_in, const int* in_sizes, int n_in,
                              void* d_out, int out_size, void* d_ws, size_t ws_size,
                              hipStream_t stream) {
    const int*   labels = (const int*)d_in[0];
    const int*   ei     = (const int*)d_in[1];
    const int*   src    = ei;
    const int*   dst    = ei + N_EDGES;
    const float* ew     = (const float*)d_in[2];
    const int*   batch  = (const int*)d_in[3];
    const float* emb    = (const float*)d_in[4];
    const float* W1 = (const float*)d_in[5],  *b1 = (const float*)d_in[6];
    const float* W2 = (const float*)d_in[7],  *b2 = (const float*)d_in[8];
    const float* W3 = (const float*)d_in[9],  *b3 = (const float*)d_in[10];
    const float* W4 = (const float*)d_in[11], *b4 = (const float*)d_in[12];
    float* out = (float*)d_out;

    // workspace carve
    float* ws   = (float*)d_ws;
    float* bufH = ws;                                       // N*64 fp32 (agg outputs / gemm input)
    float* bufA = bufH + (size_t)N_NODES * HIDDEN;          // N*64 fp32 region: barr, then A1 (fp16)
    int2*  csr  = (int2*)(bufA + (size_t)N_NODES * HIDDEN); // E int2
    int*   bcnt   = (int*)(csr + N_EDGES);                  // NBKT
    int*   boff   = bcnt + NBKT;                            // NBKT+1
    int*   bktCur = boff + NBKT + 1;                        // NBKT
    int*   off    = bktCur + NBKT;                          // N+1
    float* dinv   = (float*)(off + N_NODES + 1);            // N
    float* gsum   = dinv + N_NODES;                         // 128*64
    int2*  barr   = (int2*)bufA;                            // aliases bufA (dead after finalize)
    __half* A1h   = (__half*)bufA;                          // fp16 activation, after finalize

    const int NT = 256;
    const int blkW = (N_NODES * 64 + NT - 1) / NT;          // wave per node
    const int blkG = (N_NODES + 63) / 64;

    // ---- CSR build ----
    zero_int_kernel<<<(NBKT + NT - 1) / NT, NT, 0, stream>>>(bcnt, NBKT);
    hist_kernel<<<NBLK_E, NT, 0, stream>>>(dst, bcnt, N_EDGES);
    scan_buckets_kernel<<<1, 1024, 0, stream>>>(bcnt, boff, bktCur, gsum);
    bucket_scatter_kernel<<<NBLK_E, NT, 0, stream>>>(src, dst, ew, bktCur, barr, N_EDGES);
    finalize_kernel<<<NBKT, NT, 0, stream>>>(barr, boff, csr, off, dinv);

    // ---- conv1: aggregate in emb-space, GEMM -> fp16 activation A1 ----
    agg_pull1_kernel<<<blkW, NT, 0, stream>>>(labels, emb, csr, off, dinv, bufH, N_NODES);
    gemm64_kernel<<<blkG, NT, 0, stream>>>(bufH, W1, b1, A1h, nullptr, nullptr, 0, N_NODES);

    // ---- conv2: aggregate A1 (fp16 gather), GEMM fused with mean-pool ----
    agg_pull2_kernel<<<blkW, NT, 0, stream>>>(A1h, csr, off, dinv, bufH, N_NODES);
    gemm64_kernel<<<blkG, NT, 0, stream>>>(bufH, W2, b2, nullptr, batch, gsum, 1, N_NODES);

    // ---- head ----
    head_kernel<<<NUM_GRAPHS, 64, 0, stream>>>(gsum, batch, W3, b3, W4, b4, out);
}